// Round 8
// baseline (188.749 us; speedup 1.0000x reference)
//
#include <hip/hip_runtime.h>

// ---------------------------------------------------------------------------
// QuantizedShaper: B=256, L=8192, DIM=256, NPAT=64, HIST=32, WIN=8, T=1024.
//
// R19 (resubmit; previous round failed on infra, kernel never ran).
// 4-hop scan with lean body + fully register-resident U.
// Model from R12-R18 (7 fits): step cost ~ 30cyc x (dependent cross-lane
// hops) + ~2cyc x instrs. R12/R14/R16: 6 hops ~ 255; R13: 12 serialized
// hops ~ 490; R15/R17: 4 hops but +body+in-loop-LDS ~ 307. R19 = 4 hops
// AND lean body AND no in-loop LDS:
//   - layout (R15/R17-validated): lane q=l&15 owns patterns 4q..4q+3,
//     replicated across the 4 rows; global max = depth-2 local fold +
//     xor1/xor2/half_mirror/mirror (4 row-confined DPP hops).
//   - Uq[32] (float4, 128 VGPR) loaded ONCE per chunk as 32 broadcast
//     ds_read_b128; scan branch has the registers (R18 branch split,
//     occupancy pinned at 1 block/CU so VGPR is free).
//   - per-slot updates use the R16/R17-validated float-mask e-trick
//     (bitwise-identical decisions; C integer-exact; v'=pA-e,
//     pA=U[i+2]-C recurrence validated R16/R18).
// Extraction = R15/R17-validated byte path on fill waves; epilogue as R18.
// Diagnostic: VGPR_Count should jump to ~160-190 (U resident).
// ---------------------------------------------------------------------------

constexpr int Bb = 256, Ll = 8192, DIMc = 256, NPAT = 64, HIST = 32, WINc = 8;
constexpr int Tt = Ll / WINc;   // 1024
constexpr int TC = 32;          // t-chunk
constexpr int NC = Tt / TC;     // 32 chunks
constexpr float CINV = 1.0f / 64.0f;

#define DPP_STAGE(m, ctrl, rmask)                                              \
  (m) = fmaxf((m), __int_as_float(__builtin_amdgcn_update_dpp(                 \
            __float_as_int(m), __float_as_int(m), (ctrl), (rmask), 0xF, false)))

#define DPP_ADDF(s, ctrl, rmask)                                               \
  do {                                                                         \
    int _si = __float_as_int(s);                                               \
    int _ti = __builtin_amdgcn_update_dpp(_si, _si, (ctrl), (rmask), 0xF, false); \
    (s) += __int_as_float(_ti);                                                \
  } while (0)

#if defined(__has_builtin)
#if __has_builtin(__builtin_amdgcn_fmed3f)
#define HAVE_MED3 1
#endif
#endif

__device__ __forceinline__ float clamp01(float t) {
#if defined(HAVE_MED3)
  return __builtin_amdgcn_fmed3f(t, 0.0f, 1.0f);
#else
  return fminf(fmaxf(t, 0.0f), 1.0f);
#endif
}

// one block per pattern p: W2[p,0..31] + bias2[p]
__global__ __launch_bounds__(256) void precompute_kernel(
    const float* __restrict__ conv_w, const float* __restrict__ conv_b,
    const float* __restrict__ keys_w, float* __restrict__ wsf) {
  __shared__ float part[8][32];
  __shared__ float bred[4];
  const int p = blockIdx.x;
  const int t = threadIdx.x;
  const int h = t & 31, g = t >> 5;
  const float* kwp = keys_w + (size_t)p * DIMc;

  float acc = 0.f;
#pragma unroll
  for (int dd = 0; dd < 32; ++dd) {
    int d = g * 32 + dd;
    acc = fmaf(kwp[d], conv_w[d * HIST + h], acc);
  }
  part[g][h] = acc;

  float bp = kwp[t] * conv_b[t];
#pragma unroll
  for (int off = 32; off; off >>= 1) bp += __shfl_down(bp, off);
  if ((t & 63) == 0) bred[t >> 6] = bp;
  __syncthreads();

  if (t < 32) {
    float s = 0.f;
#pragma unroll
    for (int gg = 0; gg < 8; ++gg) s += part[gg][t];
    wsf[(t >> 2) * (NPAT * 4) + p * 4 + (t & 3)] = s;  // float4-friendly
  } else if (t == 32) {
    wsf[NPAT * HIST + p] = (bred[0] + bred[1]) + (bred[2] + bred[3]);
  }
}

__global__ __launch_bounds__(256) void shaper_kernel(
    const float* __restrict__ x, const float* __restrict__ avg_init,
    const float* __restrict__ shapes_w, const float* __restrict__ wsf,
    float* __restrict__ out) {
  __shared__ __align__(16) float xpad[HIST - 1 + Ll + 1];
  __shared__ __align__(16) float scb[2][TC * NPAT];
  __shared__ unsigned int bmw[2][4][16];  // per-chunk win masks, dbuf
  __shared__ unsigned char idx8[Tt];      // winner pattern per step
  __shared__ float shp[WINc * NPAT];

  const int b    = blockIdx.x;
  const int tid  = threadIdx.x;
  const int wid  = tid >> 6;
  const int lane = tid & 63;
  const float* xrow = x + (size_t)b * Ll;

  // ---- stage x (left-padded) + shapes into LDS (all waves) ----
  if (tid < HIST - 1) xpad[tid] = 0.f;
  {
    const float4* xv4 = (const float4*)xrow;
#pragma unroll
    for (int k = 0; k < 8; ++k) {
      int i4 = k * 256 + tid;
      float4 v = xv4[i4];
      float* dst = xpad + HIST - 1 + i4 * 4;
      dst[0] = v.x; dst[1] = v.y; dst[2] = v.z; dst[3] = v.w;
    }
  }
  for (int i = tid; i < WINc * NPAT; i += 256) shp[i] = shapes_w[i];

  // ---- av0 via DPP-sum butterfly (all waves; validated R5/R8/R10) ----
  float av0;
  {
    float s = avg_init[(size_t)b * NPAT + lane];
    float t = s;
    DPP_ADDF(t, 0xB1, 0xF);
    DPP_ADDF(t, 0x4E, 0xF);
    DPP_ADDF(t, 0x141, 0xF);
    DPP_ADDF(t, 0x140, 0xF);
    DPP_ADDF(t, 0x142, 0xA);
    DPP_ADDF(t, 0x143, 0xC);   // lane63 = total
    float tot = __int_as_float(__builtin_amdgcn_readlane(__float_as_int(t), 63));
    av0 = s - tot * CINV;
  }

  __syncthreads();  // S1: staging complete (both paths)

  constexpr float SC75 = 37778931862957161709568.0f;  // 2^75

  if (wid == 0) {
    // =====================================================================
    // SCAN PATH (wave 0). 4 slots/lane, replicated across rows; Uq[32]
    // register-resident; 4 DPP hops per step; no LDS/SALU/VCC in loop.
    // =====================================================================
    float C0 = 0.f, C1 = 0.f, C2 = 0.f, C3 = 0.f;
    __syncthreads();  // S2: fill(0) done

    for (int c = 0; c < NC; ++c) {
      const float4* sv = (const float4*)(scb[c & 1]) + (lane & 15);
      float4 Uq[TC];
#pragma unroll
      for (int i = 0; i < TC; ++i) Uq[i] = sv[i * 16];  // broadcast b128
      float bmA0 = 0.f, bmA1 = 0.f, bmA2 = 0.f, bmA3 = 0.f;
      float bmB0 = 0.f, bmB1 = 0.f, bmB2 = 0.f, bmB3 = 0.f;
      float v0 = Uq[0].x - C0, v1 = Uq[0].y - C1;
      float v2 = Uq[0].z - C2, v3 = Uq[0].w - C3;
      float pA0 = Uq[1].x - C0, pA1 = Uq[1].y - C1;
      float pA2 = Uq[1].z - C2, pA3 = Uq[1].w - C3;
#pragma unroll
      for (int i = 0; i < TC; ++i) {
        float g = fmaxf(fmaxf(v0, v1), fmaxf(v2, v3));
        DPP_STAGE(g, 0xB1, 0xF);   // xor1  (quad)
        DPP_STAGE(g, 0x4E, 0xF);   // xor2  (quad)
        DPP_STAGE(g, 0x141, 0xF);  // row_half_mirror -> 8-group max
        DPP_STAGE(g, 0x140, 0xF);  // row_mirror -> 16-lane (=global) max
        float d0 = g - v0, d1 = g - v1, d2 = g - v2, d3 = g - v3;
        float e0 = clamp01(__builtin_fmaf(d0 * SC75, -SC75, 1.0f));
        float e1 = clamp01(__builtin_fmaf(d1 * SC75, -SC75, 1.0f));
        float e2 = clamp01(__builtin_fmaf(d2 * SC75, -SC75, 1.0f));
        float e3 = clamp01(__builtin_fmaf(d3 * SC75, -SC75, 1.0f));
        C0 += e0; C1 += e1; C2 += e2; C3 += e3;
        if (i < 16) {
          float w = (float)(1u << i);
          bmA0 = __builtin_fmaf(e0, w, bmA0);
          bmA1 = __builtin_fmaf(e1, w, bmA1);
          bmA2 = __builtin_fmaf(e2, w, bmA2);
          bmA3 = __builtin_fmaf(e3, w, bmA3);
        } else {
          float w = (float)(1u << (i - 16));
          bmB0 = __builtin_fmaf(e0, w, bmB0);
          bmB1 = __builtin_fmaf(e1, w, bmB1);
          bmB2 = __builtin_fmaf(e2, w, bmB2);
          bmB3 = __builtin_fmaf(e3, w, bmB3);
        }
        if (i + 1 < TC) {
          v0 = pA0 - e0;  v1 = pA1 - e1;
          v2 = pA2 - e2;  v3 = pA3 - e3;
          if (i + 2 < TC) {
            pA0 = Uq[i + 2].x - C0; pA1 = Uq[i + 2].y - C1;
            pA2 = Uq[i + 2].z - C2; pA3 = Uq[i + 2].w - C3;
          }
        }
      }
      if (lane < 16) {
        bmw[c & 1][0][lane] = (unsigned int)bmA0 | ((unsigned int)bmB0 << 16);
        bmw[c & 1][1][lane] = (unsigned int)bmA1 | ((unsigned int)bmB1 << 16);
        bmw[c & 1][2][lane] = (unsigned int)bmA2 | ((unsigned int)bmB2 << 16);
        bmw[c & 1][3][lane] = (unsigned int)bmA3 | ((unsigned int)bmB3 << 16);
      }
      __syncthreads();  // S3..S34
    }
    __syncthreads();  // S35: final extract done
  } else {
    // =====================================================================
    // FILL + EXTRACT PATH (waves 1-3).
    // =====================================================================
    float4 w2v[8];
    {
      const float4* w2g = (const float4*)wsf;
#pragma unroll
      for (int h4 = 0; h4 < 8; ++h4) w2v[h4] = w2g[h4 * 64 + lane];
    }
    float b2 = wsf[NPAT * HIST + lane];

    // fill chunk c (bitwise-identical to R12-R18; do not touch fma order)
    auto fill = [&](int c, float* __restrict__ sb) {
      int base = c * TC;
      for (int tl = wid - 1; tl < TC; tl += 3) {
        int t = base + tl;
        const float4* xw = (const float4*)(xpad + t * WINc);  // 32B-aligned
        float acc = b2;
#pragma unroll
        for (int h4 = 0; h4 < 8; ++h4) {
          float4 xv = xw[h4];
          float4 wv = w2v[h4];
          acc = fmaf(xv.x, wv.x, acc);
          acc = fmaf(xv.y, wv.y, acc);
          acc = fmaf(xv.z, wv.z, acc);
          acc = fmaf(xv.w, wv.w, acc);
        }
        float sc = fminf(fmaxf(acc, 0.f), 6.f);
        sb[tl * NPAT + lane] = (sc - av0) + (float)t * CINV;
      }
    };

    // batched winner extraction for chunk cc, split across waves 1-3
    // (R15/R17-validated byte path; pattern = 4*(lane&15) + slot)
    auto extract3 = [&](int cc) {
      unsigned int m0 = bmw[cc & 1][0][lane & 15];
      unsigned int m1 = bmw[cc & 1][1][lane & 15];
      unsigned int m2 = bmw[cc & 1][2][lane & 15];
      unsigned int m3 = bmw[cc & 1][3][lane & 15];
      for (int i = wid - 1; i < TC; i += 3) {
        unsigned long long k0 = __ballot(((m0 >> i) & 1u) != 0u) & 0xFFFFull;
        unsigned long long k1 = __ballot(((m1 >> i) & 1u) != 0u) & 0xFFFFull;
        unsigned long long k2 = __ballot(((m2 >> i) & 1u) != 0u) & 0xFFFFull;
        unsigned long long k3 = __ballot(((m3 >> i) & 1u) != 0u) & 0xFFFFull;
        int w = 0;
        if (k0) w = 4 * (int)(__ffsll(k0) - 1) + 0;
        if (k1) w = 4 * (int)(__ffsll(k1) - 1) + 1;
        if (k2) w = 4 * (int)(__ffsll(k2) - 1) + 2;
        if (k3) w = 4 * (int)(__ffsll(k3) - 1) + 3;
        if (lane == 0) idx8[cc * TC + i] = (unsigned char)w;
      }
    };

    fill(0, scb[0]);
    __syncthreads();  // S2

    for (int c = 0; c < NC; ++c) {
      if (c + 1 < NC) fill(c + 1, scb[(c + 1) & 1]);
      if (c >= 1) extract3(c - 1);
      __syncthreads();  // S3..S34
    }
    extract3(NC - 1);
    __syncthreads();  // S35
  }

  // ---- epilogue: out[b,l] = relu(shapes[l&7, idx[l>>3]] - x[b,l]) ----
  float4* outv = (float4*)(out + (size_t)b * Ll);
#pragma unroll
  for (int k = 0; k < 8; ++k) {
    int i4 = k * 256 + tid;
    int l0 = i4 * 4;
    int t  = l0 >> 3;
    int w0 = l0 & 7;
    int p  = (int)idx8[t];
    float4 o;
    o.x = fmaxf(shp[(w0 + 0) * NPAT + p] - xpad[HIST - 1 + l0 + 0], 0.f);
    o.y = fmaxf(shp[(w0 + 1) * NPAT + p] - xpad[HIST - 1 + l0 + 1], 0.f);
    o.z = fmaxf(shp[(w0 + 2) * NPAT + p] - xpad[HIST - 1 + l0 + 2], 0.f);
    o.w = fmaxf(shp[(w0 + 3) * NPAT + p] - xpad[HIST - 1 + l0 + 3], 0.f);
    outv[i4] = o;
  }
}

extern "C" void kernel_launch(void* const* d_in, const int* in_sizes, int n_in,
                              void* d_out, int out_size, void* d_ws, size_t ws_size,
                              hipStream_t stream) {
  const float* x        = (const float*)d_in[0];
  const float* avg_init = (const float*)d_in[1];
  const float* conv_w   = (const float*)d_in[2];
  const float* conv_b   = (const float*)d_in[3];
  const float* keys_w   = (const float*)d_in[4];
  const float* shapes_w = (const float*)d_in[5];
  float* wsf = (float*)d_ws;

  precompute_kernel<<<NPAT, 256, 0, stream>>>(conv_w, conv_b, keys_w, wsf);
  shaper_kernel<<<Bb, 256, 0, stream>>>(x, avg_init, shapes_w, wsf,
                                        (float*)d_out);
}